// Round 9
// baseline (4624.638 us; speedup 1.0000x reference)
//
#include <hip/hip_runtime.h>
#include <stdint.h>
#include <stddef.h>

// Problem constants
#define B_   32
#define S_   512
#define D_   768
#define H_   1024
#define NF_  50
#define NR_  35
#define NRP_ 36       // R logit row padded to even for b64 moves
#define NWG  256      // 64 j-slices x 2 half-batches x 2 cells
#define WGS  256

// ws layout (bytes):
//   [0,32768)        wtag[256] : dword at wg*32   (1 line per writer WG, monotone step tag)
//   [32768,65536)    itBuf[2][64][32] tagged b64 {f32 item, u32 stag} (row = 256 B)
//   [65536, ...)     pf partial logits [buf][cell][b][w][npad]
//   [1703936, ...)   xbf  (fragment-ordered bf16, see xcvt)
#define ITB_OFF   32768
#define PF_OFF    65536
#define XBF_OFF   1703936
#define PF_F_SZ   102400            // 32*64*50 floats
#define PF_STEP   176128            // + 32*64*36 floats

typedef __attribute__((ext_vector_type(8))) short sh8;   // 8 x bf16 MFMA operand
typedef __attribute__((ext_vector_type(4))) float f4;
typedef __attribute__((ext_vector_type(2))) float f2v;
typedef __attribute__((ext_vector_type(4))) unsigned int u4x;
typedef unsigned long long u64;

__device__ __forceinline__ unsigned short f2bf(float f) {
  unsigned int u = __float_as_uint(f);
  u += 0x7fffu + ((u >> 16) & 1u);
  return (unsigned short)(u >> 16);
}

// packed RNE bf16 convert: dst.lo = bf16(lo), dst.hi = bf16(hi).
__device__ __forceinline__ unsigned cvtpk_bf16(float lo, float hi) {
  unsigned r;
  asm("v_cvt_pk_bf16_f32 %0, %1, %2" : "=v"(r) : "v"(lo), "v"(hi));
  return r;
}

__device__ __forceinline__ sh8 cvt8(const float* __restrict__ p) {
  f4 av = *(const f4*)p;
  f4 bv = *(const f4*)(p + 4);
  union { sh8 s; unsigned short us[8]; } r;
  r.us[0] = f2bf(av[0]); r.us[1] = f2bf(av[1]); r.us[2] = f2bf(av[2]); r.us[3] = f2bf(av[3]);
  r.us[4] = f2bf(bv[0]); r.us[5] = f2bf(bv[1]); r.us[6] = f2bf(bv[2]); r.us[7] = f2bf(bv[3]);
  return r.s;
}

__device__ __forceinline__ float sigm(float x) { return 1.f / (1.f + __expf(-x)); }

__device__ __forceinline__ float tanhfast(float x) {
  const float e = __expf(2.f * x);
  return 1.f - 2.f / (e + 1.f);
}

__device__ __forceinline__ u64 pack2(float a, float b) {
  return (u64)__float_as_uint(a) | ((u64)__float_as_uint(b) << 32);
}

// tagged b64: value in low 32, step tag in high 32 (single-copy atomic unit)
__device__ __forceinline__ u64 tagv(float v, unsigned t) {
  return (u64)__float_as_uint(v) | ((u64)t << 32);
}
__device__ __forceinline__ float    valof(u64 p) { return __uint_as_float((unsigned)p); }
__device__ __forceinline__ unsigned tagof(u64 p) { return (unsigned)(p >> 32); }

// ---- phase 3: partial logits for this WG's 16 batches
template<int NA, int NPAIR>
__device__ __forceinline__ void pf_store(int tid, int wIdx, int b0,
                                         const float* __restrict__ h_lds,
                                         const float* __restrict__ Wa_l,
                                         u64* __restrict__ d64) {
  const int tot = 16 * NPAIR;
  for (int i = tid; i < tot; i += WGS) {
    const int bl = i / NPAIR, k = i - bl * NPAIR;
    const int n0 = 2 * k, n1 = 2 * k + 1;
    float v0 = 0.f, v1 = 0.f;
    #pragma unroll
    for (int jj = 0; jj < 16; ++jj) v0 += h_lds[bl * 16 + jj] * Wa_l[n0 * 17 + jj];
    if (n1 < NA) {
      #pragma unroll
      for (int jj = 0; jj < 16; ++jj) v1 += h_lds[bl * 16 + jj] * Wa_l[n1 * 17 + jj];
    }
    __hip_atomic_store(&d64[(size_t)((b0 + bl) * 64 + wIdx) * NPAIR + k], pack2(v0, v1),
                       __ATOMIC_RELAXED, __HIP_MEMORY_SCOPE_AGENT);
  }
}

// ---- phase 4: wave-decoupled gather+reduce -> softmax -> item (tagged publish)
// wave w: poll its 16 writers -> stage its 16 rows -> partial reduce.
// Summation order identical to the monolithic version (w2 0..15 per wave).
template<int NAR, int NAPR>
__device__ __forceinline__ void reduce_tail(
    int tid, int wave, int lane,
    const unsigned int* __restrict__ wtagG, unsigned stag,   // group's 64 tag lines
    const u64* __restrict__ src64, float* __restrict__ stage,
    float (* __restrict__ red4)[64], float* __restrict__ arow,
    const float* __restrict__ bA, const float* __restrict__ WL, float sc,
    u64* __restrict__ itRowT,
    float* __restrict__ outRow)
{
  // poll MY wave's 16 writers (4 lanes alias each tag line -> 16 line loads)
  {
    const int w = wave * 16 + (lane & 15);
    for (;;) {
      const unsigned int v = __hip_atomic_load(&wtagG[w * 32],
                                               __ATOMIC_RELAXED, __HIP_MEMORY_SCOPE_AGENT);
      if (__ballot(v >= stag) == ~0ull) break;
      __builtin_amdgcn_s_sleep(1);
    }
  }
  // stage MY wave's 16 writer rows (overlaps other waves' straggler wait)
  u64* st64 = (u64*)stage;
  constexpr int n64w = (16 * NAPR) >> 1;
  for (int i = lane; i < n64w; i += 64)
    st64[wave * n64w + i] = __hip_atomic_load(&src64[wave * n64w + i],
                                              __ATOMIC_RELAXED, __HIP_MEMORY_SCOPE_AGENT);
  // partial reduce MY rows (reads only what this wave staged)
  {
    const int n = (lane < NAR) ? lane : 0;
    float v = 0.f;
    #pragma unroll
    for (int w2 = 0; w2 < 16; ++w2) v += stage[(wave * 16 + w2) * NAPR + n];
    red4[wave][lane] = v;
  }
  __syncthreads();
  if (wave == 0) {
    const int n = (lane < NAR) ? lane : 0;
    const float v = red4[0][lane] + red4[1][lane] + red4[2][lane] + red4[3][lane];
    float e = (lane < NAR) ? __expf(v + bA[n]) : 0.f;
    float ssum = e;
    #pragma unroll
    for (int off = 1; off < 64; off <<= 1) ssum += __shfl_xor(ssum, off, 64);
    const float a = e / ssum;
    if (lane < NAR) arow[lane] = a;
    // item dot split across lane halves: dr = lane&31, k-halves combined via shfl
    {
      constexpr int KH = (NAR + 1) >> 1;
      const int dr = lane & 31;
      float it = 0.f;
      if (lane < 32) {
        #pragma unroll
        for (int k = 0; k < KH; ++k) it += arow[k] * WL[dr * NAR + k];
      } else {
        #pragma unroll
        for (int k = KH; k < NAR; ++k) it += arow[k] * WL[dr * NAR + k];
      }
      it += __shfl_xor(it, 32, 64);
      // tagged publish: value+tag in one b64 -> no drain, no rtag, no 2nd gather
      if (lane < 32)
        __hip_atomic_store(&itRowT[lane], tagv(it * sc, stag),
                           __ATOMIC_RELAXED, __HIP_MEMORY_SCOPE_AGENT);
    }
    if (lane < NAR) outRow[lane] = a;   // off the critical path
  }
}

// ---------------------------------------------------------------- init ws
__global__ void init_ws(unsigned int* __restrict__ flags) {
  const int t = blockIdx.x * blockDim.x + threadIdx.x;
  const int stride = gridDim.x * blockDim.x;
  for (int i = t; i < 16384; i += stride)   // wtag 32 KB + itBuf 32 KB
    __hip_atomic_store(&flags[i], 0u, __ATOMIC_RELAXED, __HIP_MEMORY_SCOPE_AGENT);
}

// ------------------------------------------------------- x fp32 -> bf16, fragment-ordered
__global__ void xcvt(const float* __restrict__ x, unsigned int* __restrict__ xb2, int ndw) {
  const int stride = gridDim.x * blockDim.x;
  for (int o = blockIdx.x * blockDim.x + threadIdx.x; o < ndw; o += stride) {
    const int e2  = o & 3;            // dword within lane's 8-short group
    const int l   = (o >> 2) & 63;    // lane
    const int tb  = o >> 8;           // (s*2+bt)*24 + t
    const int t   = tb % 24;
    const int bts = tb / 24;
    const int bt  = bts & 1;
    const int s   = bts >> 1;
    const int b   = bt * 16 + (l & 15);
    const int k   = t * 32 + (l >> 4) * 8 + e2 * 2;
    const f2v v = ((const f2v*)x)[(((size_t)b * S_ + s) * D_ + k) >> 1];
    xb2[o] = (unsigned int)f2bf(v[0]) | ((unsigned int)f2bf(v[1]) << 16);
  }
}

// ---------------------------------------------------------- persistent
__global__ __launch_bounds__(WGS, 1) void tpr_persist(
    const float* __restrict__ x, const unsigned short* __restrict__ xbf, int xmode,
    const float* __restrict__ WihF, const float* __restrict__ WhhF,
    const float* __restrict__ bihF, const float* __restrict__ bhhF,
    const float* __restrict__ WihR, const float* __restrict__ WhhR,
    const float* __restrict__ bihR, const float* __restrict__ bhhR,
    const float* __restrict__ WaFw, const float* __restrict__ WaFb,
    const float* __restrict__ WaRw, const float* __restrict__ WaRb,
    const float* __restrict__ Fw, const float* __restrict__ Rw,
    const float* __restrict__ scFp, const float* __restrict__ scRp,
    float* __restrict__ out0, unsigned char* __restrict__ ws)
{
  __shared__ __align__(16) float part[4][16 * 69];           // 17664 B; reused as pf stage
  __shared__ float h_lds[16 * 16];
  __shared__ __align__(16) float itF_l[16 * 36];             // this WG's 16 batches
  __shared__ __align__(16) float itR_l[16 * 36];
  __shared__ float Fw_l[32 * NF_];
  __shared__ float Rw_l[32 * NR_];
  __shared__ float Wa_l[NF_ * 17];
  __shared__ float red4[4][64];
  __shared__ float arow[64];
  __shared__ float bias_l[64];
  __shared__ float bF_l[NF_];
  __shared__ float bR_l[NR_];
  __shared__ unsigned int dsCnt;       // per-WG wave-arrival counter (monotone)

  const int wg    = blockIdx.x;
  const int tid   = threadIdx.x;
  const int wave  = tid >> 6;
  const int lane  = tid & 63;
  const int n16   = lane & 15;
  const int quad  = lane >> 4;
  const int group = wg >> 6;           // 0:F-h0 1:F-h1 2:R-h0 3:R-h1
  const bool isF  = wg < 128;
  const int hb    = group & 1;         // batch half
  const int b0    = hb * 16;           // global batch base
  const int wIdx  = wg & 63;           // j-slice within (cell,half)
  const int j0    = wIdx * 16;
  const int gbase = group << 6;        // first wg of my writer group
  const float* Wih = isF ? WihF : WihR;
  const float* Whh = isF ? WhhF : WhhR;
  const float* bih = isF ? bihF : bihR;
  const float* bhh = isF ? bhhF : bhhR;
  const float* Wa  = isF ? WaFw : WaRw;
  const int NA  = isF ? NF_ : NR_;

  unsigned int* wtag = (unsigned int*)ws;
  u64* itb = (u64*)(ws + ITB_OFF);     // [2][64][32] tagged
  float* pf    = (float*)(ws + PF_OFF);

  // ---- resident weight fragments: wave owns K-quarter; 4 gate n-tiles
  sh8 whhf[4][8];
  sh8 wihf[4][6];
  #pragma unroll
  for (int g = 0; g < 4; ++g) {
    const int row = g * 1024 + j0 + n16;
    #pragma unroll
    for (int ks = 0; ks < 8; ++ks)
      whhf[g][ks] = cvt8(Whh + (size_t)row * H_ + wave * 256 + ks * 32 + quad * 8);
    #pragma unroll
    for (int ks = 0; ks < 6; ++ks)
      wihf[g][ks] = cvt8(Wih + (size_t)row * D_ + wave * 192 + ks * 32 + quad * 8);
  }

  if (tid == 0) dsCnt = 0u;
  if (tid < 64) {
    const int row = (tid >> 4) * 1024 + j0 + (tid & 15);
    bias_l[tid] = bih[row] + bhh[row];
  }
  for (int i = tid; i < NA * 16; i += WGS)
    Wa_l[(i >> 4) * 17 + (i & 15)] = Wa[(size_t)(i >> 4) * H_ + j0 + (i & 15)];
  for (int i = tid; i < 32 * NF_; i += WGS) Fw_l[i] = Fw[i];
  for (int i = tid; i < 32 * NR_; i += WGS) Rw_l[i] = Rw[i];
  if (tid < NF_) bF_l[tid] = WaFb[tid];
  if (tid < NR_) bR_l[tid] = WaRb[tid];
  const float sF = scFp[0];
  const float sR = scRp[0];
  float cc = 0.f;

  f4 xacc[4];
  const f4 fz = {0.f, 0.f, 0.f, 0.f};

  auto xpart = [&](int sx) {
    #pragma unroll
    for (int g = 0; g < 4; ++g) xacc[g] = fz;
    #pragma unroll
    for (int ks = 0; ks < 6; ++ks) {
      sh8 xa;
      if (xmode == 0) {
        const size_t toff = ((size_t)((sx * 2 + hb) * 24 + wave * 6 + ks) << 9)
                            + (size_t)lane * 8;
        union { u4x u; sh8 s; } t;
        t.u = *(const u4x*)(xbf + toff);
        xa = t.s;
      } else {
        const size_t off = ((size_t)(b0 + n16) * S_ + sx) * D_ + wave * 192 + ks * 32 + quad * 8;
        xa = cvt8(x + off);
      }
      #pragma unroll
      for (int g = 0; g < 4; ++g)
        xacc[g] = __builtin_amdgcn_mfma_f32_16x16x32_bf16(xa, wihf[g][ks], xacc[g], 0, 0, 0);
    }
  };

  xpart(0);
  __syncthreads();

  float* out1 = out0 + (size_t)B_ * S_ * H_;
  float* out2 = out1 + (size_t)B_ * S_ * NF_;

  // reducers: wIdx 0..15 of each group; batch = b0 + wIdx
  const bool isRed = (wIdx < 16);
  const int  redB  = b0 + wIdx;                  // global batch
  const bool redF  = isF;
  const int  redJ  = (redF ? 0 : 32) + redB;     // itBuf row index

  for (int s = 0; s < S_; ++s) {
    const int buf = s & 1;
    const unsigned int stag = (unsigned int)(s + 1);

    // ---- 1. gates = xacc + T(s-1) @ Whh^T, T fragment fused from items
    f4 acc[4];
    #pragma unroll
    for (int g = 0; g < 4; ++g) acc[g] = xacc[g];
    if (s > 0) {
      const f4 fA0 = *(const f4*)&itF_l[n16 * 36 + (wave << 3)];
      const f4 fA1 = *(const f4*)&itF_l[n16 * 36 + (wave << 3) + 4];
      const f4 rA0 = *(const f4*)&itR_l[n16 * 36 + (quad << 3)];
      const f4 rA1 = *(const f4*)&itR_l[n16 * 36 + (quad << 3) + 4];
      #pragma unroll
      for (int ks = 0; ks < 8; ++ks) {
        const float fs = (ks < 4) ? fA0[ks & 3] : fA1[ks & 3];
        union { sh8 s8; u4x u; } t;
        t.u[0] = cvtpk_bf16(fs * rA0[0], fs * rA0[1]);
        t.u[1] = cvtpk_bf16(fs * rA0[2], fs * rA0[3]);
        t.u[2] = cvtpk_bf16(fs * rA1[0], fs * rA1[1]);
        t.u[3] = cvtpk_bf16(fs * rA1[2], fs * rA1[3]);
        #pragma unroll
        for (int g = 0; g < 4; ++g)
          acc[g] = __builtin_amdgcn_mfma_f32_16x16x32_bf16(t.s8, whhf[g][ks], acc[g], 0, 0, 0);
      }
    }
    #pragma unroll
    for (int g = 0; g < 4; ++g)
      #pragma unroll
      for (int r = 0; r < 4; ++r)
        part[wave][(quad * 4 + r) * 69 + g * 16 + n16] = acc[g][r];
    __syncthreads();

    // ---- 2. cross-wave reduce -> nonlinearity -> c,h  (256 thr = 16b x 16j)
    {
      const int bl = tid >> 4;
      const int jj = tid & 15;
      float G[4];
      #pragma unroll
      for (int g = 0; g < 4; ++g) {
        const int n = g * 16 + jj;
        G[g] = bias_l[n] + part[0][bl * 69 + n] + part[1][bl * 69 + n]
                         + part[2][bl * 69 + n] + part[3][bl * 69 + n];
      }
      const float ig = sigm(G[0]);
      const float fg = sigm(G[1]);
      const float gg = tanhfast(G[2]);
      const float og = sigm(G[3]);
      cc = fg * cc + ig * gg;
      h_lds[bl * 16 + jj] = og * tanhfast(cc);
    }
    __syncthreads();

    // ---- 3. partial logits -> pf, then PER-WAVE drain + LDS-counter tag
    //      (no full-WG barrier: 4th-arriving wave publishes the tag)
    if (isF)
      pf_store<NF_, (NF_ >> 1)>(tid, wIdx, b0, h_lds, Wa_l,
          (u64*)(pf + (size_t)buf * PF_STEP));
    else
      pf_store<NR_, (NRP_ >> 1)>(tid, wIdx, b0, h_lds, Wa_l,
          (u64*)(pf + (size_t)buf * PF_STEP + PF_F_SZ));
    __asm__ __volatile__("s_waitcnt vmcnt(0)" ::: "memory");  // this wave's pf at LLC
    if (lane == 0) {
      const unsigned int old = __hip_atomic_fetch_add(&dsCnt, 1u,
                                    __ATOMIC_RELAXED, __HIP_MEMORY_SCOPE_WORKGROUP);
      if (old == 4u * stag - 1u)   // I am the last of this WG's 4 waves this step
        __hip_atomic_store(&wtag[wg * 32], stag, __ATOMIC_RELAXED, __HIP_MEMORY_SCOPE_AGENT);
    }

    // ---- 4. reducers: wave-decoupled poll/gather/reduce -> publish
    if (isRed) {
      if (redF)
        reduce_tail<NF_, NF_>(tid, wave, lane,
            &wtag[gbase * 32], stag,
            (const u64*)(pf + (size_t)buf * PF_STEP + (size_t)redB * 64 * NF_),
            &part[0][0], red4, arow, bF_l, Fw_l, sF,
            &itb[((size_t)buf * 64 + redJ) * 32],
            &out1[((size_t)redB * S_ + s) * NF_]);
      else
        reduce_tail<NR_, NRP_>(tid, wave, lane,
            &wtag[gbase * 32], stag,
            (const u64*)(pf + (size_t)buf * PF_STEP + PF_F_SZ + (size_t)redB * 64 * NRP_),
            &part[0][0], red4, arow, bR_l, Rw_l, sR,
            &itb[((size_t)buf * 64 + redJ) * 32],
            &out2[((size_t)redB * S_ + s) * NR_]);
    }

    // ---- 5. overlap: next step's x-projection
    if (s + 1 < S_) xpart(s + 1);

    // ---- 6+7. poll my half's 32 tagged item rows; last poll round IS the gather
    {
      const u64* src = itb + (size_t)buf * 64 * 32;
      float vals[4];
      unsigned sm = 0;
      #pragma unroll
      for (int k2 = 0; k2 < 4; ++k2) {
        const int i = tid + k2 * WGS;       // 0..1023 = 32 rows x 32 cols
        const int lr = i >> 5, col = i & 31;
        const int grow = (lr < 16) ? (b0 + lr) : (32 + b0 + (lr - 16));
        const u64 p = __hip_atomic_load(&src[(size_t)grow * 32 + col],
                                        __ATOMIC_RELAXED, __HIP_MEMORY_SCOPE_AGENT);
        vals[k2] = valof(p);
        sm |= (tagof(p) != stag) ? (1u << k2) : 0u;
      }
      while (sm) {
        __builtin_amdgcn_s_sleep(1);
        #pragma unroll
        for (int k2 = 0; k2 < 4; ++k2) if (sm & (1u << k2)) {
          const int i = tid + k2 * WGS;
          const int lr = i >> 5, col = i & 31;
          const int grow = (lr < 16) ? (b0 + lr) : (32 + b0 + (lr - 16));
          const u64 p = __hip_atomic_load(&src[(size_t)grow * 32 + col],
                                          __ATOMIC_RELAXED, __HIP_MEMORY_SCOPE_AGENT);
          if (tagof(p) == stag) { vals[k2] = valof(p); sm &= ~(1u << k2); }
        }
      }
      #pragma unroll
      for (int k2 = 0; k2 < 4; ++k2) {
        const int i = tid + k2 * WGS;
        const int lr = i >> 5, col = i & 31;
        if (lr < 16) itF_l[lr * 36 + col] = vals[k2];
        else         itR_l[(lr - 16) * 36 + col] = vals[k2];
      }
    }
    __syncthreads();

    // ---- 8. out0 = outer(itemF,itemR) by wIdx 32..47 of F groups
    if (isF && wIdx >= 32 && wIdx < 48) {
      const int bl = wIdx - 32;
      const int ds = tid >> 3, dr0 = (tid & 7) * 4;
      f4 v;
      #pragma unroll
      for (int q = 0; q < 4; ++q) v[q] = itF_l[bl * 36 + ds] * itR_l[bl * 36 + dr0 + q];
      *(f4*)&out0[((size_t)(b0 + bl) * S_ + s) * H_ + tid * 4] = v;
    }
    // no loop-end barrier: itF_l/itR_l next written only after next step's
    // phase-6/7 barrier; part[] rewritten after phase-1's own barrier.
  }
}

// ------------------------------------------------------------- launcher
extern "C" void kernel_launch(void* const* d_in, const int* in_sizes, int n_in,
                              void* d_out, int out_size, void* d_ws, size_t ws_size,
                              hipStream_t stream) {
  (void)in_sizes; (void)n_in; (void)out_size;
  const float* x    = (const float*)d_in[0];
  const float* WihF = (const float*)d_in[1];
  const float* WhhF = (const float*)d_in[2];
  const float* bihF = (const float*)d_in[3];
  const float* bhhF = (const float*)d_in[4];
  const float* WihR = (const float*)d_in[5];
  const float* WhhR = (const float*)d_in[6];
  const float* bihR = (const float*)d_in[7];
  const float* bihR2= (const float*)d_in[8];
  const float* WaFw = (const float*)d_in[9];
  const float* WaFb = (const float*)d_in[10];
  const float* WaRw = (const float*)d_in[11];
  const float* WaRb = (const float*)d_in[12];
  const float* Fw   = (const float*)d_in[13];
  const float* Rw   = (const float*)d_in[14];
  const float* scF  = (const float*)d_in[15];
  const float* scR  = (const float*)d_in[16];

  unsigned char* ws = (unsigned char*)d_ws;
  unsigned short* xbf = (unsigned short*)(ws + XBF_OFF);
  const size_t need = (size_t)XBF_OFF + (size_t)B_ * S_ * D_ * 2;
  const int xmode = (ws_size >= need) ? 0 : 1;

  init_ws<<<8, 256, 0, stream>>>((unsigned int*)ws);
  if (xmode == 0)
    xcvt<<<2048, 256, 0, stream>>>(x, (unsigned int*)xbf, (B_ * S_ * D_) / 2);
  tpr_persist<<<NWG, WGS, 0, stream>>>(x, xbf, xmode,
      WihF, WhhF, bihF, bhhF, WihR, WhhR, bihR, bihR2,
      WaFw, WaFb, WaRw, WaRb, Fw, Rw, scF, scR,
      (float*)d_out, ws);
}

// Round 10
// 4314.811 us; speedup vs baseline: 1.0718x; 1.0718x over previous
//
#include <hip/hip_runtime.h>
#include <stdint.h>
#include <stddef.h>

// Problem constants
#define B_   32
#define S_   512
#define D_   768
#define H_   1024
#define NF_  50
#define NR_  35
#define NRP_ 36       // R logit row padded to even for b64 moves
#define NWG  256      // 64 j-slices x 2 half-batches x 2 cells
#define WGS  256

// ws layout (bytes):
//   [0,32768)        wtag[256] : dword at wg*32   (1 line per writer WG, monotone step tag)
//   [32768,65536)    itBuf[2][64][32] tagged b64 {f32 item, u32 stag} (row = 256 B)
//   [65536, ...)     pf partial logits [buf][cell][b][w][npad]
//   [1703936, ...)   xbf  (fragment-ordered bf16, see xcvt)
#define ITB_OFF   32768
#define PF_OFF    65536
#define XBF_OFF   1703936
#define PF_F_SZ   102400            // 32*64*50 floats
#define PF_STEP   176128            // + 32*64*36 floats

typedef __attribute__((ext_vector_type(8))) short sh8;   // 8 x bf16 MFMA operand
typedef __attribute__((ext_vector_type(4))) float f4;
typedef __attribute__((ext_vector_type(2))) float f2v;
typedef __attribute__((ext_vector_type(4))) unsigned int u4x;
typedef unsigned long long u64;

__device__ __forceinline__ unsigned short f2bf(float f) {
  unsigned int u = __float_as_uint(f);
  u += 0x7fffu + ((u >> 16) & 1u);
  return (unsigned short)(u >> 16);
}

// packed RNE bf16 convert: dst.lo = bf16(lo), dst.hi = bf16(hi).
__device__ __forceinline__ unsigned cvtpk_bf16(float lo, float hi) {
  unsigned r;
  asm("v_cvt_pk_bf16_f32 %0, %1, %2" : "=v"(r) : "v"(lo), "v"(hi));
  return r;
}

__device__ __forceinline__ sh8 cvt8(const float* __restrict__ p) {
  f4 av = *(const f4*)p;
  f4 bv = *(const f4*)(p + 4);
  union { sh8 s; unsigned short us[8]; } r;
  r.us[0] = f2bf(av[0]); r.us[1] = f2bf(av[1]); r.us[2] = f2bf(av[2]); r.us[3] = f2bf(av[3]);
  r.us[4] = f2bf(bv[0]); r.us[5] = f2bf(bv[1]); r.us[6] = f2bf(bv[2]); r.us[7] = f2bf(bv[3]);
  return r.s;
}

__device__ __forceinline__ float sigm(float x) { return 1.f / (1.f + __expf(-x)); }

__device__ __forceinline__ float tanhfast(float x) {
  const float e = __expf(2.f * x);
  return 1.f - 2.f / (e + 1.f);
}

__device__ __forceinline__ u64 pack2(float a, float b) {
  return (u64)__float_as_uint(a) | ((u64)__float_as_uint(b) << 32);
}

// tagged b64: value in low 32, step tag in high 32 (single-copy atomic unit)
__device__ __forceinline__ u64 tagv(float v, unsigned t) {
  return (u64)__float_as_uint(v) | ((u64)t << 32);
}
__device__ __forceinline__ float    valof(u64 p) { return __uint_as_float((unsigned)p); }
__device__ __forceinline__ unsigned tagof(u64 p) { return (unsigned)(p >> 32); }

// ---- phase 3: partial logits for this WG's 16 batches
template<int NA, int NPAIR>
__device__ __forceinline__ void pf_store(int tid, int wIdx, int b0,
                                         const float* __restrict__ h_lds,
                                         const float* __restrict__ Wa_l,
                                         u64* __restrict__ d64) {
  const int tot = 16 * NPAIR;
  for (int i = tid; i < tot; i += WGS) {
    const int bl = i / NPAIR, k = i - bl * NPAIR;
    const int n0 = 2 * k, n1 = 2 * k + 1;
    float v0 = 0.f, v1 = 0.f;
    #pragma unroll
    for (int jj = 0; jj < 16; ++jj) v0 += h_lds[bl * 16 + jj] * Wa_l[n0 * 17 + jj];
    if (n1 < NA) {
      #pragma unroll
      for (int jj = 0; jj < 16; ++jj) v1 += h_lds[bl * 16 + jj] * Wa_l[n1 * 17 + jj];
    }
    __hip_atomic_store(&d64[(size_t)((b0 + bl) * 64 + wIdx) * NPAIR + k], pack2(v0, v1),
                       __ATOMIC_RELAXED, __HIP_MEMORY_SCOPE_AGENT);
  }
}

// ---- phase 4 tail: gather 64 rows -> reduce -> softmax -> item (tagged publish)
template<int NAR, int NAPR>
__device__ __forceinline__ void reduce_tail(
    int tid, int wave, int lane,
    const u64* __restrict__ src64, float* __restrict__ stage,
    float (* __restrict__ red4)[64], float* __restrict__ arow,
    const float* __restrict__ bA, const float* __restrict__ WL, float sc,
    u64* __restrict__ itRowT, unsigned stag,
    float* __restrict__ outRow)
{
  u64* st64 = (u64*)stage;
  constexpr int n64 = (64 * NAPR) >> 1;
  for (int i = tid; i < n64; i += WGS)
    st64[i] = __hip_atomic_load(&src64[i], __ATOMIC_RELAXED, __HIP_MEMORY_SCOPE_AGENT);
  __syncthreads();
  {
    const int n = (lane < NAR) ? lane : 0;
    float v = 0.f;
    #pragma unroll
    for (int w2 = 0; w2 < 16; ++w2) v += stage[(wave * 16 + w2) * NAPR + n];
    red4[wave][lane] = v;
  }
  __syncthreads();
  if (wave == 0) {
    const int n = (lane < NAR) ? lane : 0;
    const float v = red4[0][lane] + red4[1][lane] + red4[2][lane] + red4[3][lane];
    float e = (lane < NAR) ? __expf(v + bA[n]) : 0.f;
    float ssum = e;
    #pragma unroll
    for (int off = 1; off < 64; off <<= 1) ssum += __shfl_xor(ssum, off, 64);
    const float a = e / ssum;
    if (lane < NAR) arow[lane] = a;
    // item dot split across lane halves: dr = lane&31, k-halves combined via shfl
    {
      constexpr int KH = (NAR + 1) >> 1;
      const int dr = lane & 31;
      float it = 0.f;
      if (lane < 32) {
        #pragma unroll
        for (int k = 0; k < KH; ++k) it += arow[k] * WL[dr * NAR + k];
      } else {
        #pragma unroll
        for (int k = KH; k < NAR; ++k) it += arow[k] * WL[dr * NAR + k];
      }
      it += __shfl_xor(it, 32, 64);
      // tagged publish: value+tag in one b64 -> no drain, no rtag, no 2nd gather
      if (lane < 32)
        __hip_atomic_store(&itRowT[lane], tagv(it * sc, stag),
                           __ATOMIC_RELAXED, __HIP_MEMORY_SCOPE_AGENT);
    }
    if (lane < NAR) outRow[lane] = a;   // off the critical path
  }
}

// ---------------------------------------------------------------- init ws
__global__ void init_ws(unsigned int* __restrict__ flags) {
  const int t = blockIdx.x * blockDim.x + threadIdx.x;
  const int stride = gridDim.x * blockDim.x;
  for (int i = t; i < 16384; i += stride)   // wtag 32 KB + itBuf 32 KB
    __hip_atomic_store(&flags[i], 0u, __ATOMIC_RELAXED, __HIP_MEMORY_SCOPE_AGENT);
}

// ------------------------------------------------------- x fp32 -> bf16, fragment-ordered
__global__ void xcvt(const float* __restrict__ x, unsigned int* __restrict__ xb2, int ndw) {
  const int stride = gridDim.x * blockDim.x;
  for (int o = blockIdx.x * blockDim.x + threadIdx.x; o < ndw; o += stride) {
    const int e2  = o & 3;            // dword within lane's 8-short group
    const int l   = (o >> 2) & 63;    // lane
    const int tb  = o >> 8;           // (s*2+bt)*24 + t
    const int t   = tb % 24;
    const int bts = tb / 24;
    const int bt  = bts & 1;
    const int s   = bts >> 1;
    const int b   = bt * 16 + (l & 15);
    const int k   = t * 32 + (l >> 4) * 8 + e2 * 2;
    const f2v v = ((const f2v*)x)[(((size_t)b * S_ + s) * D_ + k) >> 1];
    xb2[o] = (unsigned int)f2bf(v[0]) | ((unsigned int)f2bf(v[1]) << 16);
  }
}

// ---------------------------------------------------------- persistent
__global__ __launch_bounds__(WGS, 1) void tpr_persist(
    const float* __restrict__ x, const unsigned short* __restrict__ xbf, int xmode,
    const float* __restrict__ WihF, const float* __restrict__ WhhF,
    const float* __restrict__ bihF, const float* __restrict__ bhhF,
    const float* __restrict__ WihR, const float* __restrict__ WhhR,
    const float* __restrict__ bihR, const float* __restrict__ bhhR,
    const float* __restrict__ WaFw, const float* __restrict__ WaFb,
    const float* __restrict__ WaRw, const float* __restrict__ WaRb,
    const float* __restrict__ Fw, const float* __restrict__ Rw,
    const float* __restrict__ scFp, const float* __restrict__ scRp,
    float* __restrict__ out0, unsigned char* __restrict__ ws)
{
  __shared__ __align__(16) float part[4][16 * 69];           // 17664 B; reused as pf stage
  __shared__ float h_lds[16 * 16];
  __shared__ __align__(16) float itF_l[16 * 36];             // this WG's 16 batches
  __shared__ __align__(16) float itR_l[16 * 36];
  __shared__ float Fw_l[32 * NF_];
  __shared__ float Rw_l[32 * NR_];
  __shared__ float Wa_l[NF_ * 17];
  __shared__ float red4[4][64];
  __shared__ float arow[64];
  __shared__ float bias_l[64];
  __shared__ float bF_l[NF_];
  __shared__ float bR_l[NR_];

  const int wg    = blockIdx.x;
  const int tid   = threadIdx.x;
  const int wave  = tid >> 6;
  const int lane  = tid & 63;
  const int n16   = lane & 15;
  const int quad  = lane >> 4;
  const int group = wg >> 6;           // 0:F-h0 1:F-h1 2:R-h0 3:R-h1
  const bool isF  = wg < 128;
  const int hb    = group & 1;         // batch half
  const int b0    = hb * 16;           // global batch base
  const int wIdx  = wg & 63;           // j-slice within (cell,half)
  const int j0    = wIdx * 16;
  const int gbase = group << 6;        // first wg of my writer group
  const float* Wih = isF ? WihF : WihR;
  const float* Whh = isF ? WhhF : WhhR;
  const float* bih = isF ? bihF : bihR;
  const float* bhh = isF ? bhhF : bhhR;
  const float* Wa  = isF ? WaFw : WaRw;
  const int NA  = isF ? NF_ : NR_;

  unsigned int* wtag = (unsigned int*)ws;
  u64* itb = (u64*)(ws + ITB_OFF);     // [2][64][32] tagged
  float* pf    = (float*)(ws + PF_OFF);

  // ---- resident weight fragments: wave owns K-quarter; 4 gate n-tiles
  sh8 whhf[4][8];
  sh8 wihf[4][6];
  #pragma unroll
  for (int g = 0; g < 4; ++g) {
    const int row = g * 1024 + j0 + n16;
    #pragma unroll
    for (int ks = 0; ks < 8; ++ks)
      whhf[g][ks] = cvt8(Whh + (size_t)row * H_ + wave * 256 + ks * 32 + quad * 8);
    #pragma unroll
    for (int ks = 0; ks < 6; ++ks)
      wihf[g][ks] = cvt8(Wih + (size_t)row * D_ + wave * 192 + ks * 32 + quad * 8);
  }

  if (tid < 64) {
    const int row = (tid >> 4) * 1024 + j0 + (tid & 15);
    bias_l[tid] = bih[row] + bhh[row];
  }
  for (int i = tid; i < NA * 16; i += WGS)
    Wa_l[(i >> 4) * 17 + (i & 15)] = Wa[(size_t)(i >> 4) * H_ + j0 + (i & 15)];
  for (int i = tid; i < 32 * NF_; i += WGS) Fw_l[i] = Fw[i];
  for (int i = tid; i < 32 * NR_; i += WGS) Rw_l[i] = Rw[i];
  if (tid < NF_) bF_l[tid] = WaFb[tid];
  if (tid < NR_) bR_l[tid] = WaRb[tid];
  const float sF = scFp[0];
  const float sR = scRp[0];
  float cc = 0.f;

  f4 xacc[4];
  const f4 fz = {0.f, 0.f, 0.f, 0.f};

  auto xpart = [&](int sx) {
    #pragma unroll
    for (int g = 0; g < 4; ++g) xacc[g] = fz;
    #pragma unroll
    for (int ks = 0; ks < 6; ++ks) {
      sh8 xa;
      if (xmode == 0) {
        const size_t toff = ((size_t)((sx * 2 + hb) * 24 + wave * 6 + ks) << 9)
                            + (size_t)lane * 8;
        union { u4x u; sh8 s; } t;
        t.u = *(const u4x*)(xbf + toff);
        xa = t.s;
      } else {
        const size_t off = ((size_t)(b0 + n16) * S_ + sx) * D_ + wave * 192 + ks * 32 + quad * 8;
        xa = cvt8(x + off);
      }
      #pragma unroll
      for (int g = 0; g < 4; ++g)
        xacc[g] = __builtin_amdgcn_mfma_f32_16x16x32_bf16(xa, wihf[g][ks], xacc[g], 0, 0, 0);
    }
  };

  xpart(0);
  __syncthreads();

  float* out1 = out0 + (size_t)B_ * S_ * H_;
  float* out2 = out1 + (size_t)B_ * S_ * NF_;

  // reducers: wIdx 0..15 of each group; batch = b0 + wIdx
  const bool isRed = (wIdx < 16);
  const int  redB  = b0 + wIdx;                  // global batch
  const bool redF  = isF;
  const int  redJ  = (redF ? 0 : 32) + redB;     // itBuf row index

  for (int s = 0; s < S_; ++s) {
    const int buf = s & 1;
    const unsigned int stag = (unsigned int)(s + 1);

    // ---- 1. gates = xacc + T(s-1) @ Whh^T, T fragment fused from items
    f4 acc[4];
    #pragma unroll
    for (int g = 0; g < 4; ++g) acc[g] = xacc[g];
    if (s > 0) {
      const f4 fA0 = *(const f4*)&itF_l[n16 * 36 + (wave << 3)];
      const f4 fA1 = *(const f4*)&itF_l[n16 * 36 + (wave << 3) + 4];
      const f4 rA0 = *(const f4*)&itR_l[n16 * 36 + (quad << 3)];
      const f4 rA1 = *(const f4*)&itR_l[n16 * 36 + (quad << 3) + 4];
      #pragma unroll
      for (int ks = 0; ks < 8; ++ks) {
        const float fs = (ks < 4) ? fA0[ks & 3] : fA1[ks & 3];
        union { sh8 s8; u4x u; } t;
        t.u[0] = cvtpk_bf16(fs * rA0[0], fs * rA0[1]);
        t.u[1] = cvtpk_bf16(fs * rA0[2], fs * rA0[3]);
        t.u[2] = cvtpk_bf16(fs * rA1[0], fs * rA1[1]);
        t.u[3] = cvtpk_bf16(fs * rA1[2], fs * rA1[3]);
        #pragma unroll
        for (int g = 0; g < 4; ++g)
          acc[g] = __builtin_amdgcn_mfma_f32_16x16x32_bf16(t.s8, whhf[g][ks], acc[g], 0, 0, 0);
      }
    }
    #pragma unroll
    for (int g = 0; g < 4; ++g)
      #pragma unroll
      for (int r = 0; r < 4; ++r)
        part[wave][(quad * 4 + r) * 69 + g * 16 + n16] = acc[g][r];
    __syncthreads();

    // ---- 2. cross-wave reduce -> nonlinearity -> c,h  (256 thr = 16b x 16j)
    {
      const int bl = tid >> 4;
      const int jj = tid & 15;
      float G[4];
      #pragma unroll
      for (int g = 0; g < 4; ++g) {
        const int n = g * 16 + jj;
        G[g] = bias_l[n] + part[0][bl * 69 + n] + part[1][bl * 69 + n]
                         + part[2][bl * 69 + n] + part[3][bl * 69 + n];
      }
      const float ig = sigm(G[0]);
      const float fg = sigm(G[1]);
      const float gg = tanhfast(G[2]);
      const float og = sigm(G[3]);
      cc = fg * cc + ig * gg;
      h_lds[bl * 16 + jj] = og * tanhfast(cc);
    }
    __syncthreads();

    // ---- 3. partial logits -> pf [b][w][npad] as b64 agent stores
    if (isF)
      pf_store<NF_, (NF_ >> 1)>(tid, wIdx, b0, h_lds, Wa_l,
          (u64*)(pf + (size_t)buf * PF_STEP));
    else
      pf_store<NR_, (NRP_ >> 1)>(tid, wIdx, b0, h_lds, Wa_l,
          (u64*)(pf + (size_t)buf * PF_STEP + PF_F_SZ));
    __syncthreads();   // vmcnt(0) drain: pf fully at LLC before tag
    if (tid == 0)
      __hip_atomic_store(&wtag[wg * 32], stag, __ATOMIC_RELAXED, __HIP_MEMORY_SCOPE_AGENT);

    // ---- 4. reducers: ballot-poll my group's 64 writer tags -> reduce -> publish
    if (isRed) {
      if (wave == 0) {
        for (;;) {
          const unsigned int v = __hip_atomic_load(&wtag[(gbase + lane) * 32],
                                                   __ATOMIC_RELAXED, __HIP_MEMORY_SCOPE_AGENT);
          if (__ballot(v >= stag) == ~0ull) break;
          __builtin_amdgcn_s_sleep(1);
        }
      }
      __syncthreads();
      if (redF)
        reduce_tail<NF_, NF_>(tid, wave, lane,
            (const u64*)(pf + (size_t)buf * PF_STEP + (size_t)redB * 64 * NF_),
            &part[0][0], red4, arow, bF_l, Fw_l, sF,
            &itb[((size_t)buf * 64 + redJ) * 32], stag,
            &out1[((size_t)redB * S_ + s) * NF_]);
      else
        reduce_tail<NR_, NRP_>(tid, wave, lane,
            (const u64*)(pf + (size_t)buf * PF_STEP + PF_F_SZ + (size_t)redB * 64 * NRP_),
            &part[0][0], red4, arow, bR_l, Rw_l, sR,
            &itb[((size_t)buf * 64 + redJ) * 32], stag,
            &out2[((size_t)redB * S_ + s) * NR_]);
    }

    // ---- 5. overlap: next step's x-projection
    if (s + 1 < S_) xpart(s + 1);

    // ---- 6+7. poll my half's 32 tagged item rows; last poll round IS the gather
    {
      const u64* src = itb + (size_t)buf * 64 * 32;
      float vals[4];
      unsigned sm = 0;
      #pragma unroll
      for (int k2 = 0; k2 < 4; ++k2) {
        const int i = tid + k2 * WGS;       // 0..1023 = 32 rows x 32 cols
        const int lr = i >> 5, col = i & 31;
        const int grow = (lr < 16) ? (b0 + lr) : (32 + b0 + (lr - 16));
        const u64 p = __hip_atomic_load(&src[(size_t)grow * 32 + col],
                                        __ATOMIC_RELAXED, __HIP_MEMORY_SCOPE_AGENT);
        vals[k2] = valof(p);
        sm |= (tagof(p) != stag) ? (1u << k2) : 0u;
      }
      while (sm) {
        __builtin_amdgcn_s_sleep(1);
        #pragma unroll
        for (int k2 = 0; k2 < 4; ++k2) if (sm & (1u << k2)) {
          const int i = tid + k2 * WGS;
          const int lr = i >> 5, col = i & 31;
          const int grow = (lr < 16) ? (b0 + lr) : (32 + b0 + (lr - 16));
          const u64 p = __hip_atomic_load(&src[(size_t)grow * 32 + col],
                                          __ATOMIC_RELAXED, __HIP_MEMORY_SCOPE_AGENT);
          if (tagof(p) == stag) { vals[k2] = valof(p); sm &= ~(1u << k2); }
        }
      }
      #pragma unroll
      for (int k2 = 0; k2 < 4; ++k2) {
        const int i = tid + k2 * WGS;
        const int lr = i >> 5, col = i & 31;
        if (lr < 16) itF_l[lr * 36 + col] = vals[k2];
        else         itR_l[(lr - 16) * 36 + col] = vals[k2];
      }
    }
    __syncthreads();

    // ---- 8. out0 = outer(itemF,itemR) by wIdx 32..47 of F groups
    if (isF && wIdx >= 32 && wIdx < 48) {
      const int bl = wIdx - 32;
      const int ds = tid >> 3, dr0 = (tid & 7) * 4;
      f4 v;
      #pragma unroll
      for (int q = 0; q < 4; ++q) v[q] = itF_l[bl * 36 + ds] * itR_l[bl * 36 + dr0 + q];
      *(f4*)&out0[((size_t)(b0 + bl) * S_ + s) * H_ + tid * 4] = v;
    }
    // no loop-end barrier: itF_l/itR_l next written only after next step's
    // phase-6/7 barrier; part[] rewritten after phase-1's own barrier.
  }
}

// ------------------------------------------------------------- launcher
extern "C" void kernel_launch(void* const* d_in, const int* in_sizes, int n_in,
                              void* d_out, int out_size, void* d_ws, size_t ws_size,
                              hipStream_t stream) {
  (void)in_sizes; (void)n_in; (void)out_size;
  const float* x    = (const float*)d_in[0];
  const float* WihF = (const float*)d_in[1];
  const float* WhhF = (const float*)d_in[2];
  const float* bihF = (const float*)d_in[3];
  const float* bhhF = (const float*)d_in[4];
  const float* WihR = (const float*)d_in[5];
  const float* WhhR = (const float*)d_in[6];
  const float* bihR = (const float*)d_in[7];
  const float* bihR2= (const float*)d_in[8];
  const float* WaFw = (const float*)d_in[9];
  const float* WaFb = (const float*)d_in[10];
  const float* WaRw = (const float*)d_in[11];
  const float* WaRb = (const float*)d_in[12];
  const float* Fw   = (const float*)d_in[13];
  const float* Rw   = (const float*)d_in[14];
  const float* scF  = (const float*)d_in[15];
  const float* scR  = (const float*)d_in[16];

  unsigned char* ws = (unsigned char*)d_ws;
  unsigned short* xbf = (unsigned short*)(ws + XBF_OFF);
  const size_t need = (size_t)XBF_OFF + (size_t)B_ * S_ * D_ * 2;
  const int xmode = (ws_size >= need) ? 0 : 1;

  init_ws<<<8, 256, 0, stream>>>((unsigned int*)ws);
  if (xmode == 0)
    xcvt<<<2048, 256, 0, stream>>>(x, (unsigned int*)xbf, (B_ * S_ * D_) / 2);
  tpr_persist<<<NWG, WGS, 0, stream>>>(x, xbf, xmode,
      WihF, WhhF, bihF, bhhF, WihR, WhhR, bihR, bihR2,
      WaFw, WaFb, WaRw, WaRb, Fw, Rw, scF, scR,
      (float*)d_out, ws);
}